// Round 14
// baseline (529.856 us; speedup 1.0000x reference)
//
#include <hip/hip_runtime.h>
#include <hip/hip_bf16.h>
#include <stdint.h>

#define M_TOK 8192
#define KDIM  4096
#define NDIM  11008

typedef float  f32x4  __attribute__((ext_vector_type(4)));
typedef int    i32x4  __attribute__((ext_vector_type(4)));
typedef unsigned short ushort8 __attribute__((ext_vector_type(8)));

__device__ __forceinline__ unsigned short f2b(float f) {
    union { float f; unsigned int i; } v; v.f = f;
    unsigned int u = v.i;
    unsigned int r = (u + 0x7fffu + ((u >> 16) & 1u)) >> 16;
    return (unsigned short)r;
}
__device__ __forceinline__ float b2f(unsigned short u) {
    union { unsigned int i; float f; } v; v.i = ((unsigned int)u) << 16; return v.f;
}

__device__ __forceinline__ void gl_lds16(const void* g, void* l) {
    __builtin_amdgcn_global_load_lds(
        (const __attribute__((address_space(1))) unsigned int*)g,
        (__attribute__((address_space(3))) unsigned int*)l, 16, 0, 0);
}

// ---------------------------------------------------------------------------
// rotpack: one block = 16 full rows. Per bg-group: stage R(16KB)+perm in LDS,
// rotate 16x256 into a bf16 LDS row buffer, track exact f32 row max in regs.
// Then quantize LDS -> xt8 (i8) directly, with S[m] wave-reduced.
// Eliminates the xt16 global round-trip (128 MB) and the pack launch.
// thread t: row r = t>>5, u = t&31 -> cols u*8..u*8+8 of each 256-col group.
// ---------------------------------------------------------------------------
__global__ __launch_bounds__(512) void rotpack_kernel(
    const float* __restrict__ x, const float* __restrict__ R,
    const int* __restrict__ perm,
    signed char* __restrict__ xt8, int* __restrict__ S, float* __restrict__ sa)
{
    __shared__ float          Rs[16 * 273];        // 17.1 KiB (banked: i*17)
    __shared__ int            ps[256];
    __shared__ unsigned short outb[16 * 4096];     // 128 KiB bf16 row buffer
    __shared__ float          rmax[16];

    const int t  = threadIdx.x;
    const int m0 = blockIdx.x * 16;
    const int r  = t >> 5;
    const int u  = t & 31;
    const int bs = u >> 1;
    const int jb = (u & 1) * 8;

    float lmax = 1e-20f;
    const float* xrow = x + (size_t)(m0 + r) * KDIM;

    for (int bg = 0; bg < 16; ++bg) {
        if (t < 256) ps[t] = perm[bg * 256 + t];
        {
            const float* Rg = R + (size_t)bg * 4096;
#pragma unroll
            for (int k = 0; k < 8; ++k) {
                const int idx = t * 8 + k;
                const int b2 = idx >> 8;
                const int i  = (idx >> 4) & 15;
                const int j  = idx & 15;
                Rs[b2 * 273 + i * 17 + j] = Rg[idx];
            }
        }
        __syncthreads();

        float xv[16];
#pragma unroll
        for (int i = 0; i < 16; ++i) xv[i] = xrow[ps[bs * 16 + i]];

        float o[8];
#pragma unroll
        for (int j = 0; j < 8; ++j) o[j] = 0.f;
#pragma unroll
        for (int i = 0; i < 16; ++i) {
            const float xi = xv[i];
            const float* Rr = &Rs[bs * 273 + i * 17 + jb];
#pragma unroll
            for (int j = 0; j < 8; ++j) o[j] += xi * Rr[j];
        }

        unsigned short os[8] __attribute__((aligned(16)));
#pragma unroll
        for (int j = 0; j < 8; ++j) {
            lmax = fmaxf(lmax, fabsf(o[j]));
            os[j] = f2b(o[j]);
        }
        *(ushort8*)&outb[r * 4096 + bg * 256 + u * 8] = *(ushort8*)os;
        __syncthreads();   // guards Rs/ps overwrite next iter + outb for phase C
    }

    // exact row max: reduce over the 32 lanes of this row (halves of a wave)
#pragma unroll
    for (int k = 1; k < 32; k <<= 1) lmax = fmaxf(lmax, __shfl_xor(lmax, k, 64));
    if (u == 0) rmax[r] = lmax;
    __syncthreads();

    const float am  = rmax[r];
    const float inv = 127.0f / am;

    int ssum = 0;
    signed char* dst = xt8 + (size_t)(m0 + r) * KDIM;
#pragma unroll
    for (int j = 0; j < 8; ++j) {
        const int cb = j * 512 + u * 16;           // i8 col base, 16 per iter
        const ushort8 v0 = *(const ushort8*)&outb[r * 4096 + cb];
        const ushort8 v1 = *(const ushort8*)&outb[r * 4096 + cb + 8];
        signed char qv[16] __attribute__((aligned(16)));
#pragma unroll
        for (int i = 0; i < 8; ++i) {
            int q0 = (int)rintf(b2f(v0[i]) * inv);
            q0 = q0 > 127 ? 127 : (q0 < -127 ? -127 : q0);
            qv[i] = (signed char)q0; ssum += q0;
            int q1 = (int)rintf(b2f(v1[i]) * inv);
            q1 = q1 > 127 ? 127 : (q1 < -127 ? -127 : q1);
            qv[8 + i] = (signed char)q1; ssum += q1;
        }
        *(int4*)(dst + cb) = *(const int4*)qv;
    }
#pragma unroll
    for (int k = 1; k < 32; k <<= 1) ssum += __shfl_xor(ssum, k, 64);
    if (u == 0) { S[m0 + r] = ssum; sa[m0 + r] = am * (1.0f / 127.0f); }
}

// ---------------------------------------------------------------------------
// qpack: qweight int32 (0..15) -> i8 exact. High-occupancy streaming.
// ---------------------------------------------------------------------------
__global__ __launch_bounds__(256) void qpack_kernel(
    const int* __restrict__ q, signed char* __restrict__ q8)
{
    const size_t base = ((size_t)blockIdx.x * 256 + threadIdx.x) * 16;
    const int4* qp = (const int4*)(q + base);
    signed char o[16] __attribute__((aligned(16)));
#pragma unroll
    for (int c = 0; c < 4; ++c) {
        const int4 v = qp[c];
        o[c*4+0] = (signed char)v.x; o[c*4+1] = (signed char)v.y;
        o[c*4+2] = (signed char)v.z; o[c*4+3] = (signed char)v.w;
    }
    *(int4*)(q8 + base) = *(const int4*)o;
}

// ---------------------------------------------------------------------------
// i8 GEMM — round-12 VERBATIM (335 us verified). 256x256 tiles, BK=128,
// pipelined TILE with reg-dbuf frags, counted WAITV(4) (never drain to 0 in
// the main loop — round-13's WAITV(0)-per-tile variant measured -6%).
// ---------------------------------------------------------------------------
#define BAR() do { asm volatile("" ::: "memory"); __builtin_amdgcn_s_barrier(); \
                   asm volatile("" ::: "memory"); } while (0)
#define WAITV(n) asm volatile("s_waitcnt vmcnt(" #n ")" ::: "memory")
#define PRIO1 __builtin_amdgcn_s_setprio(1)
#define PRIO0 __builtin_amdgcn_s_setprio(0)

#define ABASE(bb) ((bb)*65536)
#define BBASE(bb) ((bb)*65536 + 32768)

#define STAGE_A(bb, kB) do { \
    gl_lds16(aStageBase + (size_t)(  0)*KDIM + (kB), lds + ABASE(bb) +     0 + wOff); \
    gl_lds16(aStageBase + (size_t)( 64)*KDIM + (kB), lds + ABASE(bb) +  8192 + wOff); \
    gl_lds16(aStageBase + (size_t)(128)*KDIM + (kB), lds + ABASE(bb) + 16384 + wOff); \
    gl_lds16(aStageBase + (size_t)(192)*KDIM + (kB), lds + ABASE(bb) + 24576 + wOff); \
} while (0)
#define STAGE_B0(bb, kB) do { \
    gl_lds16(bStageBase + (size_t)(  0)*KDIM + (kB), lds + BBASE(bb) +     0 + wOff); \
    gl_lds16(bStageBase + (size_t)( 64)*KDIM + (kB), lds + BBASE(bb) +  8192 + wOff); \
} while (0)
#define STAGE_B1(bb, kB) do { \
    gl_lds16(bStageBase + (size_t)(128)*KDIM + (kB), lds + BBASE(bb) + 16384 + wOff); \
    gl_lds16(bStageBase + (size_t)(192)*KDIM + (kB), lds + BBASE(bb) + 24576 + wOff); \
} while (0)

#define PH_READ_A2(bb, mh, dst) do { \
    _Pragma("unroll") \
    for (int mf = 0; mf < 4; ++mf) { \
        dst[mf][0] = *(const i32x4*)(lds + ABASE(bb) + aRdBase + ((mh)*64 + mf*16)*128 + cs0); \
        dst[mf][1] = *(const i32x4*)(lds + ABASE(bb) + aRdBase + ((mh)*64 + mf*16)*128 + cs1); \
    } \
} while (0)
#define PH_READ_B2(bb, nh, dst) do { \
    _Pragma("unroll") \
    for (int nf = 0; nf < 2; ++nf) { \
        dst[nf][0] = *(const i32x4*)(lds + BBASE(bb) + bRdBase + ((nh)*32 + nf*16)*128 + cs0); \
        dst[nf][1] = *(const i32x4*)(lds + BBASE(bb) + bRdBase + ((nh)*32 + nf*16)*128 + cs1); \
    } \
} while (0)

#define MFMA_QX(mh, nh, Aset, Bset) do { \
    _Pragma("unroll") \
    for (int mf = 0; mf < 4; ++mf) \
    _Pragma("unroll") \
    for (int nf = 0; nf < 2; ++nf) { \
        acc[(mh)*4+mf][(nh)*2+nf] = __builtin_amdgcn_mfma_i32_16x16x64_i8( \
            Aset[mf][0], Bset[nf][0], acc[(mh)*4+mf][(nh)*2+nf], 0, 0, 0); \
        acc[(mh)*4+mf][(nh)*2+nf] = __builtin_amdgcn_mfma_i32_16x16x64_i8( \
            Aset[mf][1], Bset[nf][1], acc[(mh)*4+mf][(nh)*2+nf], 0, 0, 0); \
    } \
} while (0)

#define TILE(bb, kB, MODE) do { \
    PH_READ_A2(bb, 0, aF0); PH_READ_B2(bb, 0, bG0); \
    if ((MODE) <= 1) STAGE_B0((bb)^1, (kB) + 128); \
    PH_READ_B2(bb, 1, bG1); \
    PRIO1; MFMA_QX(0, 0, aF0, bG0); PRIO0; \
    if ((MODE) <= 1) STAGE_B1((bb)^1, (kB) + 128); \
    PH_READ_A2(bb, 1, aF1); \
    PRIO1; MFMA_QX(0, 1, aF0, bG1); PRIO0; \
    BAR(); \
    if ((MODE) == 0) STAGE_A(bb, (kB) + 256); \
    PRIO1; MFMA_QX(1, 0, aF1, bG0); PRIO0; \
    PRIO1; MFMA_QX(1, 1, aF1, bG1); PRIO0; \
    if ((MODE) == 0) WAITV(4); \
    if ((MODE) == 1) WAITV(0); \
    BAR(); \
} while (0)

// tail (128x256) path
#define TAB(bb) ((bb)*16384)
#define TBB(bb) (32768 + (bb)*32768)

#define STAGE_TA(bb, kB) do { \
    gl_lds16(aStageBase + (size_t)(  0)*KDIM + (kB), lds + TAB(bb) +    0 + wOff); \
    gl_lds16(aStageBase + (size_t)( 64)*KDIM + (kB), lds + TAB(bb) + 8192 + wOff); \
} while (0)
#define STAGE_TB0(bb, kB) do { \
    gl_lds16(bStageBase + (size_t)(  0)*KDIM + (kB), lds + TBB(bb) +     0 + wOff); \
    gl_lds16(bStageBase + (size_t)( 64)*KDIM + (kB), lds + TBB(bb) +  8192 + wOff); \
} while (0)
#define STAGE_TB1(bb, kB) do { \
    gl_lds16(bStageBase + (size_t)(128)*KDIM + (kB), lds + TBB(bb) + 16384 + wOff); \
    gl_lds16(bStageBase + (size_t)(192)*KDIM + (kB), lds + TBB(bb) + 24576 + wOff); \
} while (0)

#define PH_READ_TA(bb) do { \
    _Pragma("unroll") \
    for (int mf = 0; mf < 4; ++mf) { \
        aF[mf][0] = *(const i32x4*)(lds + TAB(bb) + aRdBase + (mf*16)*128 + cs0); \
        aF[mf][1] = *(const i32x4*)(lds + TAB(bb) + aRdBase + (mf*16)*128 + cs1); \
    } \
} while (0)
#define PH_READ_TB(bb, nh) do { \
    _Pragma("unroll") \
    for (int nf = 0; nf < 2; ++nf) { \
        bF[nh][nf][0] = *(const i32x4*)(lds + TBB(bb) + bRdBase + ((nh)*32 + nf*16)*128 + cs0); \
        bF[nh][nf][1] = *(const i32x4*)(lds + TBB(bb) + bRdBase + ((nh)*32 + nf*16)*128 + cs1); \
    } \
} while (0)

#define MFMA_TQ(nh) do { \
    _Pragma("unroll") \
    for (int mf = 0; mf < 4; ++mf) \
    _Pragma("unroll") \
    for (int nf = 0; nf < 2; ++nf) { \
        acc[mf][(nh)*2+nf] = __builtin_amdgcn_mfma_i32_16x16x64_i8( \
            aF[mf][0], bF[nh][nf][0], acc[mf][(nh)*2+nf], 0, 0, 0); \
        acc[mf][(nh)*2+nf] = __builtin_amdgcn_mfma_i32_16x16x64_i8( \
            aF[mf][1], bF[nh][nf][1], acc[mf][(nh)*2+nf], 0, 0, 0); \
    } \
} while (0)

#define TTILE(bb, kB, MODE) do { \
    PH_READ_TA(bb); PH_READ_TB(bb, 0); \
    if ((MODE) <= 1) STAGE_TB0((bb)^1, (kB) + 128); \
    BAR(); PRIO1; MFMA_TQ(0); PRIO0; BAR(); \
    PH_READ_TB(bb, 1); \
    if ((MODE) <= 1) STAGE_TB1((bb)^1, (kB) + 128); \
    BAR(); PRIO1; MFMA_TQ(1); PRIO0; \
    if ((MODE) == 0) STAGE_TA(bb, (kB) + 256); \
    if ((MODE) == 0) WAITV(2); \
    if ((MODE) == 1) WAITV(0); \
    BAR(); \
} while (0)

__global__ __launch_bounds__(512, 2) void gemm_all(
    const signed char* __restrict__ Aq, const signed char* __restrict__ Bq,
    const float* __restrict__ sn, const float* __restrict__ zz,
    const float* __restrict__ sa, const int* __restrict__ S,
    float* __restrict__ C)
{
    __shared__ char lds[131072];

    const int tid  = threadIdx.x;
    const int wave = tid >> 6;
    const int lane = tid & 63;
    const int wr   = wave >> 2;
    const int wc   = wave & 3;
    const int wg   = blockIdx.x;

    const int gRow    = wave * 8 + (lane >> 3);
    const int gColSwz = (((lane & 7) ^ ((lane >> 3) & 7)) << 4);
    const int wOff    = wave * 1024;

    const int laneRow128 = (lane & 15) * 128;
    const int lx  = (lane & 7) << 4;
    const int cs0 = (((lane >> 4) * 16)      ) ^ lx;   // k 0..63
    const int cs1 = (((lane >> 4) * 16) + 64 ) ^ lx;   // k 64..127

    if (wg < 1280) {
        // ================= MAIN: 256x256, tn 0..39 =================
        const int swz = (wg & 7) * 160 + (wg >> 3);
        const int Sx = swz >> 7;
        const int L  = swz & 127;
        const int tm = L >> 2;
        const int tn = (Sx << 2) + (L & 3);

        const char* aStageBase = (const char*)Aq + (size_t)(tm * 256 + gRow) * KDIM + gColSwz;
        const char* bStageBase = (const char*)Bq + (size_t)(tn * 256 + gRow) * KDIM + gColSwz;

        const int aRdBase = wr * 16384 + laneRow128;
        const int bRdBase = (wc >> 1) * 16384 + (wc & 1) * 8192 + laneRow128;

        i32x4 acc[8][4] = {};
        i32x4 aF0[4][2], aF1[4][2];
        i32x4 bG0[2][2], bG1[2][2];

        STAGE_A(0, 0);
        STAGE_B0(0, 0); STAGE_B1(0, 0);
        STAGE_A(1, 128);
        WAITV(4);
        BAR();

        int kB = 0;
#pragma unroll 1
        for (int t = 0; t < 29; t += 2) {       // 32 K-tiles of BK=128
            TILE(0, kB, 0);
            TILE(1, kB + 128, 0);
            kB += 256;
        }
        TILE(0, 30 * 128, 1);
        TILE(1, 31 * 128, 2);

        const int row0 = tm * 256 + wr * 128 + (lane >> 4) * 4;
        const int col0 = tn * 256 + wc * 64 + (lane & 15);
        float sn4[4], z4[4];
#pragma unroll
        for (int ni = 0; ni < 4; ++ni) { sn4[ni] = sn[col0 + ni*16]; z4[ni] = zz[col0 + ni*16]; }
#pragma unroll
        for (int mi = 0; mi < 8; ++mi) {
            const int rbase = row0 + mi * 16;
            float sa4[4], Sf4[4];
#pragma unroll
            for (int j = 0; j < 4; ++j) { sa4[j] = sa[rbase + j]; Sf4[j] = (float)S[rbase + j]; }
#pragma unroll
            for (int ni = 0; ni < 4; ++ni) {
                const i32x4 v = acc[mi][ni];
                const int c = col0 + ni * 16;
#pragma unroll
                for (int j = 0; j < 4; ++j)
                    C[(size_t)(rbase + j) * NDIM + c] = sa4[j] * sn4[ni] * ((float)v[j] - z4[ni] * Sf4[j]);
            }
        }
    } else {
        // ================= TAIL: 128x256, tn 40..42 =================
        const int h   = wg - 1280;
        const int tn  = 40 + (h % 3);
        const int tmh = h / 3;

        const char* aStageBase = (const char*)Aq + (size_t)(tmh * 128 + gRow) * KDIM + gColSwz;
        const char* bStageBase = (const char*)Bq + (size_t)(tn * 256 + gRow) * KDIM + gColSwz;

        const int aRdBase = wr * 8192 + laneRow128;
        const int bRdBase = (wc >> 1) * 16384 + (wc & 1) * 8192 + laneRow128;

        i32x4 acc[4][4] = {};
        i32x4 aF[4][2];
        i32x4 bF[2][2][2];

        STAGE_TA(0, 0);
        STAGE_TB0(0, 0); STAGE_TB1(0, 0);
        STAGE_TA(1, 128);
        WAITV(2);
        BAR();

        int kB = 0;
#pragma unroll 1
        for (int t = 0; t < 29; t += 2) {
            TTILE(0, kB, 0);
            TTILE(1, kB + 128, 0);
            kB += 256;
        }
        TTILE(0, 30 * 128, 1);
        TTILE(1, 31 * 128, 2);

        const int row0 = tmh * 128 + wr * 64 + (lane >> 4) * 4;
        const int col0 = tn * 256 + wc * 64 + (lane & 15);
        float sn4[4], z4[4];
#pragma unroll
        for (int ni = 0; ni < 4; ++ni) { sn4[ni] = sn[col0 + ni*16]; z4[ni] = zz[col0 + ni*16]; }
#pragma unroll
        for (int mi = 0; mi < 4; ++mi) {
            const int rbase = row0 + mi * 16;
            float sa4[4], Sf4[4];
#pragma unroll
            for (int j = 0; j < 4; ++j) { sa4[j] = sa[rbase + j]; Sf4[j] = (float)S[rbase + j]; }
#pragma unroll
            for (int ni = 0; ni < 4; ++ni) {
                const i32x4 v = acc[mi][ni];
                const int c = col0 + ni * 16;
#pragma unroll
                for (int j = 0; j < 4; ++j)
                    C[(size_t)(rbase + j) * NDIM + c] = sa4[j] * sn4[ni] * ((float)v[j] - z4[ni] * Sf4[j]);
            }
        }
    }
}

extern "C" void kernel_launch(void* const* d_in, const int* in_sizes, int n_in,
                              void* d_out, int out_size, void* d_ws, size_t ws_size,
                              hipStream_t stream) {
    const float* x      = (const float*)d_in[0];
    const float* R      = (const float*)d_in[1];
    const float* scales = (const float*)d_in[2];
    const float* zeros  = (const float*)d_in[3];
    const int*   perm   = (const int*)d_in[4];
    const int*   qw     = (const int*)d_in[5];
    float*       out    = (float*)d_out;

    // workspace layout (bytes)
    char* ws = (char*)d_ws;
    signed char* xt8 = (signed char*)ws;                      // 32 MiB @ 0
    signed char* q8  = (signed char*)(ws + 33554432);         // 43 MiB
    float*       sa  = (float*)(ws + 78643200);               // 32 KiB
    int*         S   = (int*)(ws + 78675968);                 // 32 KiB

    rotpack_kernel<<<dim3(M_TOK / 16), 512, 0, stream>>>(x, R, perm, xt8, S, sa);
    qpack_kernel<<<dim3((int)(((size_t)NDIM * KDIM) / 16 / 256)), 256, 0, stream>>>(qw, q8);
    gemm_all<<<dim3(1472), 512, 0, stream>>>(xt8, q8, scales, zeros, sa, S, out);
}

// Round 15
// 427.663 us; speedup vs baseline: 1.2390x; 1.2390x over previous
//
#include <hip/hip_runtime.h>
#include <hip/hip_bf16.h>
#include <stdint.h>

#define M_TOK 8192
#define KDIM  4096
#define NDIM  11008

typedef float  f32x4  __attribute__((ext_vector_type(4)));
typedef int    i32x4  __attribute__((ext_vector_type(4)));
typedef unsigned short ushort8 __attribute__((ext_vector_type(8)));

__device__ __forceinline__ unsigned short f2b(float f) {
    union { float f; unsigned int i; } v; v.f = f;
    unsigned int u = v.i;
    unsigned int r = (u + 0x7fffu + ((u >> 16) & 1u)) >> 16;
    return (unsigned short)r;
}
__device__ __forceinline__ float b2f(unsigned short u) {
    union { unsigned int i; float f; } v; v.i = ((unsigned int)u) << 16; return v.f;
}

__device__ __forceinline__ void gl_lds16(const void* g, void* l) {
    __builtin_amdgcn_global_load_lds(
        (const __attribute__((address_space(1))) unsigned int*)g,
        (__attribute__((address_space(3))) unsigned int*)l, 16, 0, 0);
}

// ---------------------------------------------------------------------------
// prep1: blocks 0..8191 rotate (+ per-256-col-group max), 8192..19199 qpack.
// Rotate gather has a contiguity fast path: when ps[bs*16+i] == base+i and
// base is 16B-aligned (true for this workload's identity perm), the 16
// scattered scalar loads become 4x float4 loads (G13). Scalar fallback keeps
// it correct for arbitrary perm.
// ---------------------------------------------------------------------------
__global__ __launch_bounds__(256) void prep1_kernel(
    const float* __restrict__ x, const float* __restrict__ R,
    const int* __restrict__ perm, const int* __restrict__ qw,
    unsigned short* __restrict__ xt, float* __restrict__ pmax,
    signed char* __restrict__ q8)
{
    const int bid = blockIdx.x;
    const int t   = threadIdx.x;

    if (bid < 8192) {
        // ---- rotate ----
        __shared__ float Rs[16 * 273];
        __shared__ int   ps[256];
        const int bg = bid & 15;
        const int mc = bid >> 4;

        ps[t] = perm[bg * 256 + t];
        {
            const float* Rg = R + (size_t)bg * 4096;
#pragma unroll
            for (int k = 0; k < 16; ++k) {
                const int idx = t * 16 + k;
                const int bs = idx >> 8;
                const int i  = (idx >> 4) & 15;
                const int j  = idx & 15;
                Rs[bs * 273 + i * 17 + j] = Rg[idx];
            }
        }
        __syncthreads();

        const int bs = t & 15;
        const int r  = t >> 4;
        const int m  = mc * 16 + r;
        const float* xrow = x + (size_t)m * KDIM;

        const int base = ps[bs * 16];
        bool contig = (base & 3) == 0;
#pragma unroll
        for (int i = 1; i < 16; ++i) contig &= (ps[bs * 16 + i] == base + i);

        float xv[16];
        if (contig) {
            const f32x4* xp = (const f32x4*)(xrow + base);
            const f32x4 a0 = xp[0], a1 = xp[1], a2 = xp[2], a3 = xp[3];
#pragma unroll
            for (int i = 0; i < 4; ++i) {
                xv[i]      = a0[i];
                xv[4 + i]  = a1[i];
                xv[8 + i]  = a2[i];
                xv[12 + i] = a3[i];
            }
        } else {
#pragma unroll
            for (int i = 0; i < 16; ++i) xv[i] = xrow[ps[bs * 16 + i]];
        }

        float o[16];
#pragma unroll
        for (int j = 0; j < 16; ++j) o[j] = 0.f;
#pragma unroll
        for (int i = 0; i < 16; ++i) {
            const float xi = xv[i];
            const float* Rrow = &Rs[bs * 273 + i * 17];
#pragma unroll
            for (int j = 0; j < 16; ++j) o[j] += xi * Rrow[j];
        }

        float lm = 0.f;
#pragma unroll
        for (int j = 0; j < 16; ++j) lm = fmaxf(lm, fabsf(o[j]));
#pragma unroll
        for (int k = 1; k < 16; k <<= 1) lm = fmaxf(lm, __shfl_xor(lm, k, 64));
        if (bs == 0) pmax[(size_t)m * 16 + bg] = lm;

        unsigned short os[16] __attribute__((aligned(16)));
#pragma unroll
        for (int j = 0; j < 16; ++j) os[j] = f2b(o[j]);
        unsigned short* dst = xt + (size_t)m * KDIM + bg * 256 + bs * 16;
        *(ushort8*)dst       = *(ushort8*)os;
        *(ushort8*)(dst + 8) = *(ushort8*)(os + 8);
    } else {
        // ---- qpack: int32 (0..15) -> i8 exact ----
        const size_t base = ((size_t)(bid - 8192) * 256 + t) * 16;
        const int4* qp = (const int4*)(qw + base);
        signed char o[16] __attribute__((aligned(16)));
#pragma unroll
        for (int c = 0; c < 4; ++c) {
            const int4 v = qp[c];
            o[c*4+0] = (signed char)v.x; o[c*4+1] = (signed char)v.y;
            o[c*4+2] = (signed char)v.z; o[c*4+3] = (signed char)v.w;
        }
        *(int4*)(q8 + base) = *(const int4*)o;
    }
}

// ---------------------------------------------------------------------------
// Pack: per-row amax -> s_a[m]; xt bf16 -> i8; S[m] = sum(xtq). 1 block/row.
// ---------------------------------------------------------------------------
__global__ __launch_bounds__(256) void pack_kernel(
    const unsigned short* __restrict__ xt, const float* __restrict__ pmax,
    signed char* __restrict__ xt8, int* __restrict__ S, float* __restrict__ sa)
{
    const int m = blockIdx.x;
    const int t = threadIdx.x;

    float am = 1e-20f;
#pragma unroll
    for (int i = 0; i < 16; ++i) am = fmaxf(am, pmax[(size_t)m * 16 + i]);
    const float inv = 127.0f / am;

    const unsigned short* src = xt + (size_t)m * KDIM + t * 16;
    ushort8 u0 = *(const ushort8*)src;
    ushort8 u1 = *(const ushort8*)(src + 8);
    signed char qv[16] __attribute__((aligned(16)));
    int s = 0;
#pragma unroll
    for (int i = 0; i < 8; ++i) {
        int q0 = (int)rintf(b2f(u0[i]) * inv);
        q0 = q0 > 127 ? 127 : (q0 < -127 ? -127 : q0);
        qv[i] = (signed char)q0; s += q0;
        int q1 = (int)rintf(b2f(u1[i]) * inv);
        q1 = q1 > 127 ? 127 : (q1 < -127 ? -127 : q1);
        qv[8 + i] = (signed char)q1; s += q1;
    }
    *(int4*)(xt8 + (size_t)m * KDIM + t * 16) = *(const int4*)qv;

#pragma unroll
    for (int k = 1; k < 64; k <<= 1) s += __shfl_xor(s, k, 64);
    __shared__ int ws[4];
    if ((t & 63) == 0) ws[t >> 6] = s;
    __syncthreads();
    if (t == 0) {
        S[m]  = ws[0] + ws[1] + ws[2] + ws[3];
        sa[m] = am * (1.0f / 127.0f);
    }
}

// ---------------------------------------------------------------------------
// i8 GEMM — round-12 VERBATIM (333-335 us verified across rounds 12/14).
// 256x256 tiles, BK=128, pipelined TILE with reg-dbuf frags, counted WAITV(4).
// ---------------------------------------------------------------------------
#define BAR() do { asm volatile("" ::: "memory"); __builtin_amdgcn_s_barrier(); \
                   asm volatile("" ::: "memory"); } while (0)
#define WAITV(n) asm volatile("s_waitcnt vmcnt(" #n ")" ::: "memory")
#define PRIO1 __builtin_amdgcn_s_setprio(1)
#define PRIO0 __builtin_amdgcn_s_setprio(0)

#define ABASE(bb) ((bb)*65536)
#define BBASE(bb) ((bb)*65536 + 32768)

#define STAGE_A(bb, kB) do { \
    gl_lds16(aStageBase + (size_t)(  0)*KDIM + (kB), lds + ABASE(bb) +     0 + wOff); \
    gl_lds16(aStageBase + (size_t)( 64)*KDIM + (kB), lds + ABASE(bb) +  8192 + wOff); \
    gl_lds16(aStageBase + (size_t)(128)*KDIM + (kB), lds + ABASE(bb) + 16384 + wOff); \
    gl_lds16(aStageBase + (size_t)(192)*KDIM + (kB), lds + ABASE(bb) + 24576 + wOff); \
} while (0)
#define STAGE_B0(bb, kB) do { \
    gl_lds16(bStageBase + (size_t)(  0)*KDIM + (kB), lds + BBASE(bb) +     0 + wOff); \
    gl_lds16(bStageBase + (size_t)( 64)*KDIM + (kB), lds + BBASE(bb) +  8192 + wOff); \
} while (0)
#define STAGE_B1(bb, kB) do { \
    gl_lds16(bStageBase + (size_t)(128)*KDIM + (kB), lds + BBASE(bb) + 16384 + wOff); \
    gl_lds16(bStageBase + (size_t)(192)*KDIM + (kB), lds + BBASE(bb) + 24576 + wOff); \
} while (0)

#define PH_READ_A2(bb, mh, dst) do { \
    _Pragma("unroll") \
    for (int mf = 0; mf < 4; ++mf) { \
        dst[mf][0] = *(const i32x4*)(lds + ABASE(bb) + aRdBase + ((mh)*64 + mf*16)*128 + cs0); \
        dst[mf][1] = *(const i32x4*)(lds + ABASE(bb) + aRdBase + ((mh)*64 + mf*16)*128 + cs1); \
    } \
} while (0)
#define PH_READ_B2(bb, nh, dst) do { \
    _Pragma("unroll") \
    for (int nf = 0; nf < 2; ++nf) { \
        dst[nf][0] = *(const i32x4*)(lds + BBASE(bb) + bRdBase + ((nh)*32 + nf*16)*128 + cs0); \
        dst[nf][1] = *(const i32x4*)(lds + BBASE(bb) + bRdBase + ((nh)*32 + nf*16)*128 + cs1); \
    } \
} while (0)

#define MFMA_QX(mh, nh, Aset, Bset) do { \
    _Pragma("unroll") \
    for (int mf = 0; mf < 4; ++mf) \
    _Pragma("unroll") \
    for (int nf = 0; nf < 2; ++nf) { \
        acc[(mh)*4+mf][(nh)*2+nf] = __builtin_amdgcn_mfma_i32_16x16x64_i8( \
            Aset[mf][0], Bset[nf][0], acc[(mh)*4+mf][(nh)*2+nf], 0, 0, 0); \
        acc[(mh)*4+mf][(nh)*2+nf] = __builtin_amdgcn_mfma_i32_16x16x64_i8( \
            Aset[mf][1], Bset[nf][1], acc[(mh)*4+mf][(nh)*2+nf], 0, 0, 0); \
    } \
} while (0)

#define TILE(bb, kB, MODE) do { \
    PH_READ_A2(bb, 0, aF0); PH_READ_B2(bb, 0, bG0); \
    if ((MODE) <= 1) STAGE_B0((bb)^1, (kB) + 128); \
    PH_READ_B2(bb, 1, bG1); \
    PRIO1; MFMA_QX(0, 0, aF0, bG0); PRIO0; \
    if ((MODE) <= 1) STAGE_B1((bb)^1, (kB) + 128); \
    PH_READ_A2(bb, 1, aF1); \
    PRIO1; MFMA_QX(0, 1, aF0, bG1); PRIO0; \
    BAR(); \
    if ((MODE) == 0) STAGE_A(bb, (kB) + 256); \
    PRIO1; MFMA_QX(1, 0, aF1, bG0); PRIO0; \
    PRIO1; MFMA_QX(1, 1, aF1, bG1); PRIO0; \
    if ((MODE) == 0) WAITV(4); \
    if ((MODE) == 1) WAITV(0); \
    BAR(); \
} while (0)

// tail (128x256) path
#define TAB(bb) ((bb)*16384)
#define TBB(bb) (32768 + (bb)*32768)

#define STAGE_TA(bb, kB) do { \
    gl_lds16(aStageBase + (size_t)(  0)*KDIM + (kB), lds + TAB(bb) +    0 + wOff); \
    gl_lds16(aStageBase + (size_t)( 64)*KDIM + (kB), lds + TAB(bb) + 8192 + wOff); \
} while (0)
#define STAGE_TB0(bb, kB) do { \
    gl_lds16(bStageBase + (size_t)(  0)*KDIM + (kB), lds + TBB(bb) +     0 + wOff); \
    gl_lds16(bStageBase + (size_t)( 64)*KDIM + (kB), lds + TBB(bb) +  8192 + wOff); \
} while (0)
#define STAGE_TB1(bb, kB) do { \
    gl_lds16(bStageBase + (size_t)(128)*KDIM + (kB), lds + TBB(bb) + 16384 + wOff); \
    gl_lds16(bStageBase + (size_t)(192)*KDIM + (kB), lds + TBB(bb) + 24576 + wOff); \
} while (0)

#define PH_READ_TA(bb) do { \
    _Pragma("unroll") \
    for (int mf = 0; mf < 4; ++mf) { \
        aF[mf][0] = *(const i32x4*)(lds + TAB(bb) + aRdBase + (mf*16)*128 + cs0); \
        aF[mf][1] = *(const i32x4*)(lds + TAB(bb) + aRdBase + (mf*16)*128 + cs1); \
    } \
} while (0)
#define PH_READ_TB(bb, nh) do { \
    _Pragma("unroll") \
    for (int nf = 0; nf < 2; ++nf) { \
        bF[nh][nf][0] = *(const i32x4*)(lds + TBB(bb) + bRdBase + ((nh)*32 + nf*16)*128 + cs0); \
        bF[nh][nf][1] = *(const i32x4*)(lds + TBB(bb) + bRdBase + ((nh)*32 + nf*16)*128 + cs1); \
    } \
} while (0)

#define MFMA_TQ(nh) do { \
    _Pragma("unroll") \
    for (int mf = 0; mf < 4; ++mf) \
    _Pragma("unroll") \
    for (int nf = 0; nf < 2; ++nf) { \
        acc[mf][(nh)*2+nf] = __builtin_amdgcn_mfma_i32_16x16x64_i8( \
            aF[mf][0], bF[nh][nf][0], acc[mf][(nh)*2+nf], 0, 0, 0); \
        acc[mf][(nh)*2+nf] = __builtin_amdgcn_mfma_i32_16x16x64_i8( \
            aF[mf][1], bF[nh][nf][1], acc[mf][(nh)*2+nf], 0, 0, 0); \
    } \
} while (0)

#define TTILE(bb, kB, MODE) do { \
    PH_READ_TA(bb); PH_READ_TB(bb, 0); \
    if ((MODE) <= 1) STAGE_TB0((bb)^1, (kB) + 128); \
    BAR(); PRIO1; MFMA_TQ(0); PRIO0; BAR(); \
    PH_READ_TB(bb, 1); \
    if ((MODE) <= 1) STAGE_TB1((bb)^1, (kB) + 128); \
    BAR(); PRIO1; MFMA_TQ(1); PRIO0; \
    if ((MODE) == 0) STAGE_TA(bb, (kB) + 256); \
    if ((MODE) == 0) WAITV(2); \
    if ((MODE) == 1) WAITV(0); \
    BAR(); \
} while (0)

__global__ __launch_bounds__(512, 2) void gemm_all(
    const signed char* __restrict__ Aq, const signed char* __restrict__ Bq,
    const float* __restrict__ sn, const float* __restrict__ zz,
    const float* __restrict__ sa, const int* __restrict__ S,
    float* __restrict__ C)
{
    __shared__ char lds[131072];

    const int tid  = threadIdx.x;
    const int wave = tid >> 6;
    const int lane = tid & 63;
    const int wr   = wave >> 2;
    const int wc   = wave & 3;
    const int wg   = blockIdx.x;

    const int gRow    = wave * 8 + (lane >> 3);
    const int gColSwz = (((lane & 7) ^ ((lane >> 3) & 7)) << 4);
    const int wOff    = wave * 1024;

    const int laneRow128 = (lane & 15) * 128;
    const int lx  = (lane & 7) << 4;
    const int cs0 = (((lane >> 4) * 16)      ) ^ lx;   // k 0..63
    const int cs1 = (((lane >> 4) * 16) + 64 ) ^ lx;   // k 64..127

    if (wg < 1280) {
        // ================= MAIN: 256x256, tn 0..39 =================
        const int swz = (wg & 7) * 160 + (wg >> 3);
        const int Sx = swz >> 7;
        const int L  = swz & 127;
        const int tm = L >> 2;
        const int tn = (Sx << 2) + (L & 3);

        const char* aStageBase = (const char*)Aq + (size_t)(tm * 256 + gRow) * KDIM + gColSwz;
        const char* bStageBase = (const char*)Bq + (size_t)(tn * 256 + gRow) * KDIM + gColSwz;

        const int aRdBase = wr * 16384 + laneRow128;
        const int bRdBase = (wc >> 1) * 16384 + (wc & 1) * 8192 + laneRow128;

        i32x4 acc[8][4] = {};
        i32x4 aF0[4][2], aF1[4][2];
        i32x4 bG0[2][2], bG1[2][2];

        STAGE_A(0, 0);
        STAGE_B0(0, 0); STAGE_B1(0, 0);
        STAGE_A(1, 128);
        WAITV(4);
        BAR();

        int kB = 0;
#pragma unroll 1
        for (int t = 0; t < 29; t += 2) {       // 32 K-tiles of BK=128
            TILE(0, kB, 0);
            TILE(1, kB + 128, 0);
            kB += 256;
        }
        TILE(0, 30 * 128, 1);
        TILE(1, 31 * 128, 2);

        const int row0 = tm * 256 + wr * 128 + (lane >> 4) * 4;
        const int col0 = tn * 256 + wc * 64 + (lane & 15);
        float sn4[4], z4[4];
#pragma unroll
        for (int ni = 0; ni < 4; ++ni) { sn4[ni] = sn[col0 + ni*16]; z4[ni] = zz[col0 + ni*16]; }
#pragma unroll
        for (int mi = 0; mi < 8; ++mi) {
            const int rbase = row0 + mi * 16;
            float sa4[4], Sf4[4];
#pragma unroll
            for (int j = 0; j < 4; ++j) { sa4[j] = sa[rbase + j]; Sf4[j] = (float)S[rbase + j]; }
#pragma unroll
            for (int ni = 0; ni < 4; ++ni) {
                const i32x4 v = acc[mi][ni];
                const int c = col0 + ni * 16;
#pragma unroll
                for (int j = 0; j < 4; ++j)
                    C[(size_t)(rbase + j) * NDIM + c] = sa4[j] * sn4[ni] * ((float)v[j] - z4[ni] * Sf4[j]);
            }
        }
    } else {
        // ================= TAIL: 128x256, tn 40..42 =================
        const int h   = wg - 1280;
        const int tn  = 40 + (h % 3);
        const int tmh = h / 3;

        const char* aStageBase = (const char*)Aq + (size_t)(tmh * 128 + gRow) * KDIM + gColSwz;
        const char* bStageBase = (const char*)Bq + (size_t)(tn * 256 + gRow) * KDIM + gColSwz;

        const int aRdBase = wr * 8192 + laneRow128;
        const int bRdBase = (wc >> 1) * 16384 + (wc & 1) * 8192 + laneRow128;

        i32x4 acc[4][4] = {};
        i32x4 aF[4][2];
        i32x4 bF[2][2][2];

        STAGE_TA(0, 0);
        STAGE_TB0(0, 0); STAGE_TB1(0, 0);
        STAGE_TA(1, 128);
        WAITV(2);
        BAR();

        int kB = 0;
#pragma unroll 1
        for (int t = 0; t < 29; t += 2) {
            TTILE(0, kB, 0);
            TTILE(1, kB + 128, 0);
            kB += 256;
        }
        TTILE(0, 30 * 128, 1);
        TTILE(1, 31 * 128, 2);

        const int row0 = tmh * 128 + wr * 64 + (lane >> 4) * 4;
        const int col0 = tn * 256 + wc * 64 + (lane & 15);
        float sn4[4], z4[4];
#pragma unroll
        for (int ni = 0; ni < 4; ++ni) { sn4[ni] = sn[col0 + ni*16]; z4[ni] = zz[col0 + ni*16]; }
#pragma unroll
        for (int mi = 0; mi < 4; ++mi) {
            const int rbase = row0 + mi * 16;
            float sa4[4], Sf4[4];
#pragma unroll
            for (int j = 0; j < 4; ++j) { sa4[j] = sa[rbase + j]; Sf4[j] = (float)S[rbase + j]; }
#pragma unroll
            for (int ni = 0; ni < 4; ++ni) {
                const i32x4 v = acc[mi][ni];
                const int c = col0 + ni * 16;
#pragma unroll
                for (int j = 0; j < 4; ++j)
                    C[(size_t)(rbase + j) * NDIM + c] = sa4[j] * sn4[ni] * ((float)v[j] - z4[ni] * Sf4[j]);
            }
        }
    }
}

extern "C" void kernel_launch(void* const* d_in, const int* in_sizes, int n_in,
                              void* d_out, int out_size, void* d_ws, size_t ws_size,
                              hipStream_t stream) {
    const float* x      = (const float*)d_in[0];
    const float* R      = (const float*)d_in[1];
    const float* scales = (const float*)d_in[2];
    const float* zeros  = (const float*)d_in[3];
    const int*   perm   = (const int*)d_in[4];
    const int*   qw     = (const int*)d_in[5];
    float*       out    = (float*)d_out;

    // workspace layout (bytes)
    char* ws = (char*)d_ws;
    unsigned short* xt16 = (unsigned short*)ws;                   //  64 MiB @ 0
    signed char*    xt8  = (signed char*)(ws + 67108864);         //  32 MiB
    signed char*    q8   = (signed char*)(ws + 100663296);        //  43 MiB
    float*          pmax = (float*)(ws + 145752064);              // 512 KiB
    float*          sa   = (float*)(ws + 146276352);              //  32 KiB
    int*            S    = (int*)(ws + 146309120);                //  32 KiB

    prep1_kernel<<<dim3(8192 + 11008), 256, 0, stream>>>(x, R, perm, qw, xt16, pmax, q8);
    pack_kernel<<<dim3(M_TOK), 256, 0, stream>>>(xt16, pmax, xt8, S, sa);
    gemm_all<<<dim3(1472), 512, 0, stream>>>(xt8, q8, scales, zeros, sa, S, out);
}